// Round 3
// baseline (318.478 us; speedup 1.0000x reference)
//
#include <hip/hip_runtime.h>

// Haar (db1) 2-D DWT, non-overlapping 2x2 block transform.
// Input:  (16, 3, 1024, 1024) fp32
// Output: 4 planes (cA, cH, cV, cD), each (16, 3, 512, 512) fp32, concat flat.
//
// Memory-bound streaming: 192 MiB read + 192 MiB write, each byte touched once.
// v3: LDS-staged wide stores.
//   - Loads unchanged: lane-contiguous 16B nontemporal dwordx4 (2 per thread).
//   - Problem with v2: stores were 8B/lane dwordx2 across 4 separate write
//     streams; fills on this box hit 6.6 TB/s with wide stores, we got ~5.65.
//   - Fix: block (256 thr) covers one full output row (512 cols) of one
//     (img, oy). Stage 4x f32x2 per thread into LDS (8B-consecutive per wave,
//     conflict-free), barrier, read back 2x ds_read_b128 (16B-consecutive,
//     conflict-free), store 2x nontemporal dwordx4 — each wave stores a fully
//     contiguous 1 KiB run of a single plane.
//   - LDS 8 KiB/block; 8 blocks/CU x 8 KiB = 64 KiB <= 160 KiB, occupancy
//     still thread-limited (8 blocks/CU).

#define IN_W   1024
#define IN_H   1024
#define IMG_IN (IN_H * IN_W)
#define OUT_W  512
#define OUT_H  512
#define IMG_OUT (OUT_H * OUT_W)
#define N_IMG  48                        // B*C = 16*3
#define PLANE  ((size_t)N_IMG * IMG_OUT) // elements per output plane

typedef float f32x4 __attribute__((ext_vector_type(4)));
typedef float f32x2 __attribute__((ext_vector_type(2)));

__global__ __launch_bounds__(256) void haar_dwt2_kernel(
    const float* __restrict__ x, float* __restrict__ out)
{
    __shared__ float lds[4 * OUT_W];   // [plane][512 cols] for this block's row

    int tid = threadIdx.x;             // == ox (16B group in input row), 0..255
    int bid = blockIdx.x;
    int oy  = bid & 511;               // output row
    int img = bid >> 9;                // (b,c) image index, 0..47

    const float* img_base = x + (size_t)img * IMG_IN;
    const f32x4* row0 = (const f32x4*)(img_base + (size_t)(2 * oy)     * IN_W);
    const f32x4* row1 = (const f32x4*)(img_base + (size_t)(2 * oy + 1) * IN_W);

    // Lane-contiguous: lane i loads 16B at index (base + i).
    f32x4 a = __builtin_nontemporal_load(row0 + tid);  // even row, cols [4t..4t+3]
    f32x4 b = __builtin_nontemporal_load(row1 + tid);  // odd  row

    // Output cols 2t, 2t+1. Arithmetic order identical to reference (absmax 0).
    f32x2 cA, cH, cV, cD;

    cA.x = (a.x + a.y + b.x + b.y) * 0.5f;
    cH.x = (a.x + a.y - b.x - b.y) * 0.5f;
    cV.x = (a.x - a.y + b.x - b.y) * 0.5f;
    cD.x = (a.x - a.y - b.x + b.y) * 0.5f;

    cA.y = (a.z + a.w + b.z + b.w) * 0.5f;
    cH.y = (a.z + a.w - b.z - b.w) * 0.5f;
    cV.y = (a.z - a.w + b.z - b.w) * 0.5f;
    cD.y = (a.z - a.w - b.z + b.w) * 0.5f;

    // Stage to LDS: per-wave 8B-consecutive writes -> conflict-free.
    int c0 = 2 * tid;
    *(f32x2*)&lds[0 * OUT_W + c0] = cA;
    *(f32x2*)&lds[1 * OUT_W + c0] = cH;
    *(f32x2*)&lds[2 * OUT_W + c0] = cV;
    *(f32x2*)&lds[3 * OUT_W + c0] = cD;

    __syncthreads();

    // Read back in store-friendly layout: thread handles 16B unit (p, g) and
    // (p+2, g). Per wave: 16B-consecutive reads -> conflict-free; stores are
    // fully contiguous 1 KiB per wave within a single plane.
    int p = tid >> 7;                  // 0 or 1
    int g = tid & 127;                 // 16B group within the 512-col row
    f32x4 u1 = *(const f32x4*)&lds[(p    ) * OUT_W + 4 * g];
    f32x4 u2 = *(const f32x4*)&lds[(p + 2) * OUT_W + 4 * g];

    size_t o_row = (size_t)img * IMG_OUT + (size_t)oy * OUT_W + (size_t)(4 * g);
    __builtin_nontemporal_store(u1, (f32x4*)(out + (size_t)(p    ) * PLANE + o_row));
    __builtin_nontemporal_store(u2, (f32x4*)(out + (size_t)(p + 2) * PLANE + o_row));
}

extern "C" void kernel_launch(void* const* d_in, const int* in_sizes, int n_in,
                              void* d_out, int out_size, void* d_ws, size_t ws_size,
                              hipStream_t stream)
{
    const float* x = (const float*)d_in[0];
    float* out = (float*)d_out;

    // One block per (img, output row): 48 * 512 = 24576 blocks of 256 threads.
    int grid = N_IMG * OUT_H;
    haar_dwt2_kernel<<<grid, 256, 0, stream>>>(x, out);
}